// Round 10
// baseline (405.354 us; speedup 1.0000x reference)
//
#include <hip/hip_runtime.h>
#include <hip/hip_fp16.h>
#include <cstdint>
#include <cstddef>

// Problem constants (fixed by reference)
#define NB      64      // batch
#define NBITS   4096
#define HD      64      // hidden
#define IN_DIM  4098
#define LMAXT   320
#define SEQ_STRIDE 336  // padded seq row (>= LMAX+2, mult of 16)
#define NTILE   257     // col tiles of 16 (4112 padded cols)
#define LOG2E   1.44269504088896340f
#define TWO_L2E 2.88539008177792680f
#define CSPLIT  8       // column-split waves per k_proj block
#define NBLK_PROJ 640
#define NGRU    32      // GRU blocks (2 rows per block/wave)

// Workspace layout (bytes)
static constexpr size_t SEQ_OFF    = 0;                              // 86016
static constexpr size_t STEPS_OFF  = 86016;                          // 256
static constexpr size_t LOSS_OFF   = 86272;                          // 4
static constexpr size_t TICK_OFF   = 86400;                          // 4
static constexpr size_t XB_OFF     = 86528;                          // 64*320*64*2
static constexpr size_t WB_OFF     = XB_OFF + 2621440;               // 257*1024*2
static constexpr size_t BO_OFF     = WB_OFF + 526336;                // 4112*4

typedef float     f32x4  __attribute__((ext_vector_type(4)));
typedef _Float16  h2     __attribute__((ext_vector_type(2)));
typedef _Float16  h8     __attribute__((ext_vector_type(8)));

#if __has_builtin(__builtin_amdgcn_fdot2)
#define FDOT2(a, b, c) __builtin_amdgcn_fdot2((a), (b), (c), false)
#else
#define FDOT2(a, b, c) fmaf((float)(a)[0], (float)(b)[0], \
                        fmaf((float)(a)[1], (float)(b)[1], (c)))
#endif

// glibc's math.h macro-expands a declaration named __exp2f -> do NOT use that
// identifier; go straight to the HW builtin (v_exp_f32).
__device__ __forceinline__ float ex2(float x) {
#if __has_builtin(__builtin_amdgcn_exp2f)
  return __builtin_amdgcn_exp2f(x);
#else
  return __expf(x * 0.6931471805599453f);
#endif
}
__device__ __forceinline__ float frcp(float x) {
#if __has_builtin(__builtin_amdgcn_rcpf)
  return __builtin_amdgcn_rcpf(x);
#else
  return 1.f / x;
#endif
}

__device__ __forceinline__ unsigned short f2h(float f) {
  return __builtin_bit_cast(unsigned short, (_Float16)f);
}
__device__ __forceinline__ float h2f(unsigned short u) {
  return (float)__builtin_bit_cast(_Float16, u);
}
__device__ __forceinline__ h8 ldh8(const unsigned short* p) {
  return *(const h8*)p;
}
__device__ __forceinline__ void wave_lds_fence() {
  __asm__ __volatile__("s_waitcnt lgkmcnt(0)" ::: "memory");
}

// R8-verified parallel prefix-sum compaction for one batch row.
// Single wave; returns nst. bits[] is scratch LDS (reused across rows —
// safe: one wave executes in lockstep, no cross-lane race).
__device__ __forceinline__ int compact_row(
    int b, const float* __restrict__ true_fp, const int* __restrict__ perm,
    unsigned long long* bits, int* seqLrow, int* srow, int j) {
  {
    const float* row = true_fp + (size_t)b * NBITS;
    const float4* rv = (const float4*)(row + j * 64);
    unsigned long long w = 0ull;
#pragma unroll
    for (int i = 0; i < 16; ++i) {
      const float4 v = rv[i];
      w |= (unsigned long long)(v.x > 0.f) << (4 * i + 0);
      w |= (unsigned long long)(v.y > 0.f) << (4 * i + 1);
      w |= (unsigned long long)(v.z > 0.f) << (4 * i + 2);
      w |= (unsigned long long)(v.w > 0.f) << (4 * i + 3);
    }
    bits[j] = w;
  }
  wave_lds_fence();

  // lane j owns cols j*64+1 .. j*64+64  ->  perm indices j*64 .. j*64+63
  unsigned long long m = 0ull;
  {
    const int4* pv = (const int4*)(perm + j * 64);
#pragma unroll
    for (int q4 = 0; q4 < 16; ++q4) {
      const int4 p4 = pv[q4];
      m |= (unsigned long long)((bits[p4.x >> 6] >> (p4.x & 63)) & 1ull) << (4 * q4 + 0);
      m |= (unsigned long long)((bits[p4.y >> 6] >> (p4.y & 63)) & 1ull) << (4 * q4 + 1);
      m |= (unsigned long long)((bits[p4.z >> 6] >> (p4.z & 63)) & 1ull) << (4 * q4 + 2);
      m |= (unsigned long long)((bits[p4.w >> 6] >> (p4.w & 63)) & 1ull) << (4 * q4 + 3);
    }
  }
  const int cnt = __popcll(m);
  int incl = cnt;
#pragma unroll
  for (int d = 1; d < 64; d <<= 1) {
    const int v = __shfl_up(incl, d, 64);
    if (j >= d) incl += v;
  }
  const int S = __shfl(incl, 63, 64);   // total set bits over cols 1..4096
  if (j == 0) { srow[0] = 0; seqLrow[0] = 0; }    // forced col 0
  {
    int idx = 1 + (incl - cnt);                   // exclusive prefix + 1
    unsigned long long mm = m;
    while (mm) {
      const int i = __builtin_ctzll(mm);
      mm &= mm - 1;
      if (idx <= LMAXT) {
        const int col = j * 64 + 1 + i;
        srow[idx] = col; seqLrow[idx] = col;
      }
      ++idx;
    }
  }
  if (j == 63) {                                  // forced col IN_DIM-1
    const int last = 1 + S;
    if (last <= LMAXT) { srow[last] = IN_DIM - 1; seqLrow[last] = IN_DIM - 1; }
  }
  const int base = S + 2;
  const int cap = (base <= LMAXT + 1) ? base : (LMAXT + 1);
  for (int i = cap + j; i < SEQ_STRIDE; i += 64) srow[i] = 0;
  for (int i = cap + j; i < LMAXT + 2; i += 64) seqLrow[i] = 0;
  int nst = S + 1;
  if (nst > LMAXT) nst = LMAXT;
  return nst;
}

// ---------------------------------------------------------------------------
// Kernel FRONT:
//   blocks 0..31   : TWO batch rows per wave. Compaction (R8) for both rows,
//                    then a 2-row GRU: 192 FDOT2/step sharing the SAME 96
//                    weight registers (W_hh is row-invariant); independent
//                    A/B chains amortize the exposed LDS/dep-chain latency
//                    that made 1-row cost ~770 cyc/step.
//   blocks 32..288 : W_out f16 tile prep (R2-verified) + loss/ticket zeroing.
// Keeps the proven shape: 64 threads, waves_per_eu(1,1) (R4-R6: any 8-wave
// variant register-starves; this adds only ~+30 VGPR to the 132 baseline).
// ---------------------------------------------------------------------------
#define W_DEF(i) h2 wr##i, wz##i, wn##i;
#define W_INIT(i) {                                                  \
    const float* w0_ = W_hh + (size_t)(2 * (i)) * 192;               \
    const float* w1_ = W_hh + (size_t)(2 * (i) + 1) * 192;           \
    wr##i[0] = (_Float16)w0_[g];       wr##i[1] = (_Float16)w1_[g];  \
    wz##i[0] = (_Float16)w0_[64 + g];  wz##i[1] = (_Float16)w1_[64 + g]; \
    wn##i[0] = (_Float16)w0_[128 + g]; wn##i[1] = (_Float16)w1_[128 + g]; }

#define W_ALIAS(i8, a, b, c, d)                                           \
  const h2 wr##i8##_0 = wr##a, wr##i8##_1 = wr##b,                        \
           wr##i8##_2 = wr##c, wr##i8##_3 = wr##d;                        \
  const h2 wz##i8##_0 = wz##a, wz##i8##_1 = wz##b,                        \
           wz##i8##_2 = wz##c, wz##i8##_3 = wz##d;                        \
  const h2 wn##i8##_0 = wn##a, wn##i8##_1 = wn##b,                        \
           wn##i8##_2 = wn##c, wn##i8##_3 = wn##d;

#define DOT8_2(i) {                                                       \
    const h8 vA_ = hpA[i];                                                \
    const h8 vB_ = hpB[i];                                                \
    const h2 a0_ = __builtin_shufflevector(vA_, vA_, 0, 1);               \
    const h2 a1_ = __builtin_shufflevector(vA_, vA_, 2, 3);               \
    const h2 a2_ = __builtin_shufflevector(vA_, vA_, 4, 5);               \
    const h2 a3_ = __builtin_shufflevector(vA_, vA_, 6, 7);               \
    const h2 c0_ = __builtin_shufflevector(vB_, vB_, 0, 1);               \
    const h2 c1_ = __builtin_shufflevector(vB_, vB_, 2, 3);               \
    const h2 c2_ = __builtin_shufflevector(vB_, vB_, 4, 5);               \
    const h2 c3_ = __builtin_shufflevector(vB_, vB_, 6, 7);               \
    srA0 = FDOT2(a0_, wr##i##_0, srA0);  srA1 = FDOT2(a1_, wr##i##_1, srA1); \
    srA0 = FDOT2(a2_, wr##i##_2, srA0);  srA1 = FDOT2(a3_, wr##i##_3, srA1); \
    srB0 = FDOT2(c0_, wr##i##_0, srB0);  srB1 = FDOT2(c1_, wr##i##_1, srB1); \
    srB0 = FDOT2(c2_, wr##i##_2, srB0);  srB1 = FDOT2(c3_, wr##i##_3, srB1); \
    szA0 = FDOT2(a0_, wz##i##_0, szA0);  szA1 = FDOT2(a1_, wz##i##_1, szA1); \
    szA0 = FDOT2(a2_, wz##i##_2, szA0);  szA1 = FDOT2(a3_, wz##i##_3, szA1); \
    szB0 = FDOT2(c0_, wz##i##_0, szB0);  szB1 = FDOT2(c1_, wz##i##_1, szB1); \
    szB0 = FDOT2(c2_, wz##i##_2, szB0);  szB1 = FDOT2(c3_, wz##i##_3, szB1); \
    snA0 = FDOT2(a0_, wn##i##_0, snA0);  snA1 = FDOT2(a1_, wn##i##_1, snA1); \
    snA0 = FDOT2(a2_, wn##i##_2, snA0);  snA1 = FDOT2(a3_, wn##i##_3, snA1); \
    snB0 = FDOT2(c0_, wn##i##_0, snB0);  snB1 = FDOT2(c1_, wn##i##_1, snB1); \
    snB0 = FDOT2(c2_, wn##i##_2, snB0);  snB1 = FDOT2(c3_, wn##i##_3, snB1); }

__global__ __launch_bounds__(64)
__attribute__((amdgpu_waves_per_eu(1, 1)))
void k_front(
    const float* __restrict__ embeds,
    const float* __restrict__ true_fp, const int* __restrict__ perm,
    const float* __restrict__ W_ih, const float* __restrict__ b_ih,
    const float* __restrict__ W_hh, const float* __restrict__ b_hh,
    const float* __restrict__ W_out, const float* __restrict__ b_out,
    int* __restrict__ seq, int* __restrict__ steps,
    unsigned short* __restrict__ Xh,
    unsigned short* __restrict__ Wh, float* __restrict__ bo2,
    float* __restrict__ loss_accum, unsigned* __restrict__ ticket) {
  const int blk = blockIdx.x;

  if (blk >= NGRU) {
    // ---- W tile prep for col tile c (R2/R9-verified 64-thread variant) ----
    const int c = blk - NGRU;            // 0..256
    const int t = threadIdx.x;           // 0..63
    if (c == 0 && t == 0) { *loss_accum = 0.f; *ticket = 0u; }
    const int m = t & 15;                // col within tile
    const int col = c * 16 + m;
    const bool cok = col < IN_DIM;
#pragma unroll
    for (int kp = 0; kp < 16; ++kp) {
      const int k = kp * 4 + (t >> 4);
      const float v = cok ? W_out[(size_t)k * IN_DIM + col] : 0.f;
      Wh[c * 1024 + m * 64 + k] = f2h(v);
    }
    if (t < 16) {
      const int cc = c * 16 + t;
      bo2[c * 16 + t] = (cc < IN_DIM) ? (b_out[cc] - 30.f) * LOG2E : -1e30f;
    }
    return;
  }

  // ---------------- blocks 0..31: 2-row compaction + GRU ----------------
  const int bA = 2 * blk;
  const int bB = 2 * blk + 1;
  const int g = threadIdx.x;   // 0..63
  const int j = g;

  __shared__ unsigned long long bits[64];
  __shared__ __align__(16) _Float16 hlA[HD];
  __shared__ __align__(16) _Float16 hlB[HD];
  __shared__ int seqLA[LMAXT + 2];
  __shared__ int seqLB[LMAXT + 2];

  // Issue the scattered W_hh register loads FIRST; latency hides under the
  // compaction (R7/R8-verified pattern).
  W_DEF(0)  W_DEF(1)  W_DEF(2)  W_DEF(3)  W_DEF(4)  W_DEF(5)  W_DEF(6)  W_DEF(7)
  W_DEF(8)  W_DEF(9)  W_DEF(10) W_DEF(11) W_DEF(12) W_DEF(13) W_DEF(14) W_DEF(15)
  W_DEF(16) W_DEF(17) W_DEF(18) W_DEF(19) W_DEF(20) W_DEF(21) W_DEF(22) W_DEF(23)
  W_DEF(24) W_DEF(25) W_DEF(26) W_DEF(27) W_DEF(28) W_DEF(29) W_DEF(30) W_DEF(31)
  W_INIT(0)  W_INIT(1)  W_INIT(2)  W_INIT(3)  W_INIT(4)  W_INIT(5)  W_INIT(6)  W_INIT(7)
  W_INIT(8)  W_INIT(9)  W_INIT(10) W_INIT(11) W_INIT(12) W_INIT(13) W_INIT(14) W_INIT(15)
  W_INIT(16) W_INIT(17) W_INIT(18) W_INIT(19) W_INIT(20) W_INIT(21) W_INIT(22) W_INIT(23)
  W_INIT(24) W_INIT(25) W_INIT(26) W_INIT(27) W_INIT(28) W_INIT(29) W_INIT(30) W_INIT(31)
  W_ALIAS(0, 0, 1, 2, 3)     W_ALIAS(1, 4, 5, 6, 7)
  W_ALIAS(2, 8, 9, 10, 11)   W_ALIAS(3, 12, 13, 14, 15)
  W_ALIAS(4, 16, 17, 18, 19) W_ALIAS(5, 20, 21, 22, 23)
  W_ALIAS(6, 24, 25, 26, 27) W_ALIAS(7, 28, 29, 30, 31)

  const float br2  = (b_ih[g]       + b_hh[g])       * -LOG2E;
  const float bz2  = (b_ih[64 + g]  + b_hh[64 + g])  * -LOG2E;
  const float bn2  = b_ih[128 + g]  * TWO_L2E;
  const float bhn2 = b_hh[128 + g]  * TWO_L2E;

  // ---- compaction for both rows (single wave, lockstep -> no race) ----
  const int nstA = compact_row(bA, true_fp, perm, bits,
                               seqLA, seq + bA * SEQ_STRIDE, j);
  wave_lds_fence();
  const int nstB = compact_row(bB, true_fp, perm, bits,
                               seqLB, seq + bB * SEQ_STRIDE, j);
  if (j == 0) { steps[bA] = nstA; steps[bB] = nstB; }
  wave_lds_fence();

  // ---- 2-row GRU recurrence ----
  float hselfA = embeds[bA * HD + g];
  float hselfB = embeds[bB * HD + g];
  hlA[g] = (_Float16)hselfA;
  hlB[g] = (_Float16)hselfB;

  unsigned short* xptrA = Xh + (size_t)bA * LMAXT * HD + g;
  unsigned short* xptrB = Xh + (size_t)bB * LMAXT * HD + g;

  // depth-4 prefetch slots, both rows (R1 fma-at-load form; R3 raw-load hurt)
  float pA0r, pA0z, pA0n, pA1r, pA1z, pA1n, pA2r, pA2z, pA2n, pA3r, pA3z, pA3n;
  float pB0r, pB0z, pB0n, pB1r, pB1z, pB1n, pB2r, pB2z, pB2n, pB3r, pB3z, pB3n;
#define PF_INIT(P, SL, k)                                                  \
  { const float* r_ = W_ih + (size_t)SL[k] * 192;                          \
    P##k##r = fmaf(r_[g], -LOG2E, br2);                                    \
    P##k##z = fmaf(r_[64 + g], -LOG2E, bz2);                               \
    P##k##n = fmaf(r_[128 + g], TWO_L2E, bn2); }
  PF_INIT(pA, seqLA, 0) PF_INIT(pA, seqLA, 1) PF_INIT(pA, seqLA, 2) PF_INIT(pA, seqLA, 3)
  PF_INIT(pB, seqLB, 0) PF_INIT(pB, seqLB, 1) PF_INIT(pB, seqLB, 2) PF_INIT(pB, seqLB, 3)
#undef PF_INIT

#define GSTEP2(u) {                                                       \
    int nt_ = t + (u) + 4; nt_ = (nt_ <= LMAXT + 1) ? nt_ : (LMAXT + 1);  \
    const int sidxA_ = seqLA[nt_];                                        \
    const int sidxB_ = seqLB[nt_];                                        \
    const h8* hpA = (const h8*)hlA;                                       \
    const h8* hpB = (const h8*)hlB;                                       \
    float srA0=0.f, srA1=0.f, szA0=0.f, szA1=0.f, snA0=0.f, snA1=0.f;     \
    float srB0=0.f, srB1=0.f, szB0=0.f, szB1=0.f, snB0=0.f, snB1=0.f;     \
    DOT8_2(0) DOT8_2(1) DOT8_2(2) DOT8_2(3)                               \
    DOT8_2(4) DOT8_2(5) DOT8_2(6) DOT8_2(7)                               \
    const float rrA = frcp(1.f + ex2(fmaf(srA0 + srA1, -LOG2E, pA##u##r)));\
    const float rrB = frcp(1.f + ex2(fmaf(srB0 + srB1, -LOG2E, pB##u##r)));\
    const float zzA = frcp(1.f + ex2(fmaf(szA0 + szA1, -LOG2E, pA##u##z)));\
    const float zzB = frcp(1.f + ex2(fmaf(szB0 + szB1, -LOG2E, pB##u##z)));\
    const float g2A = fmaf(snA0 + snA1, TWO_L2E, bhn2);                   \
    const float g2B = fmaf(snB0 + snB1, TWO_L2E, bhn2);                   \
    const float qA  = frcp(1.f + ex2(fmaf(rrA, g2A, pA##u##n)));          \
    const float qB  = frcp(1.f + ex2(fmaf(rrB, g2B, pB##u##n)));          \
    const float thA = fmaf(-2.f, qA, 1.f);                                \
    const float thB = fmaf(-2.f, qB, 1.f);                                \
    const float hnA = fmaf(zzA, hselfA - thA, thA);                       \
    const float hnB = fmaf(zzB, hselfB - thB, thB);                       \
    hselfA = hnA; hselfB = hnB;                                           \
    const _Float16 hhA = (_Float16)hnA;                                   \
    const _Float16 hhB = (_Float16)hnB;                                   \
    hlA[g] = hhA; hlB[g] = hhB;                                           \
    xptrA[(size_t)(t + (u)) * HD] = __builtin_bit_cast(unsigned short, hhA);\
    xptrB[(size_t)(t + (u)) * HD] = __builtin_bit_cast(unsigned short, hhB);\
    const float* rwA_ = W_ih + (size_t)sidxA_ * 192;                      \
    pA##u##r = fmaf(rwA_[g], -LOG2E, br2);                                \
    pA##u##z = fmaf(rwA_[64 + g], -LOG2E, bz2);                           \
    pA##u##n = fmaf(rwA_[128 + g], TWO_L2E, bn2);                         \
    const float* rwB_ = W_ih + (size_t)sidxB_ * 192;                      \
    pB##u##r = fmaf(rwB_[g], -LOG2E, br2);                                \
    pB##u##z = fmaf(rwB_[64 + g], -LOG2E, bz2);                           \
    pB##u##n = fmaf(rwB_[128 + g], TWO_L2E, bn2); }

  const int nstMax = (nstA > nstB) ? nstA : nstB;
  const int ngroups = (nstMax + 3) >> 2;
  for (int tg = 0; tg < ngroups; ++tg) {
    const int t = tg * 4;
    GSTEP2(0)
    GSTEP2(1)
    GSTEP2(2)
    GSTEP2(3)
  }
#undef GSTEP2

  // zero-fill padded rows for both batch rows (overwrites garbage tail
  // stores, including the short row's overshoot steps — same-wave program
  // order guarantees the fill lands after the loop's stores).
  {
    uint4 z4; z4.x = 0u; z4.y = 0u; z4.z = 0u; z4.w = 0u;
    uint4* xzA = (uint4*)(Xh + (size_t)bA * (LMAXT * HD) + (size_t)nstA * HD);
    const int n4A = (LMAXT - nstA) * 8;
    for (int i = g; i < n4A; i += 64) xzA[i] = z4;
    uint4* xzB = (uint4*)(Xh + (size_t)bB * (LMAXT * HD) + (size_t)nstB * HD);
    const int n4B = (LMAXT - nstB) * 8;
    for (int i = g; i < n4B; i += 64) xzB[i] = z4;
  }
}

// ---------------------------------------------------------------------------
// Kernel C: MFMA f16 fused projection + logsumexp + NLL.
// Finalize folded in via device-scope atomic ticket (R2-verified).
// ---------------------------------------------------------------------------
__global__ __launch_bounds__(512)
__attribute__((amdgpu_waves_per_eu(4, 8)))
void k_proj(
    const unsigned short* __restrict__ Xh,
    const unsigned short* __restrict__ Wh,
    const float* __restrict__ bo2,
    const int* __restrict__ seq, const int* __restrict__ steps,
    const float* __restrict__ b_out,
    float* __restrict__ loss_accum, unsigned* __restrict__ ticket,
    float* __restrict__ out) {
  const int l  = threadIdx.x & 63;
  const int wv = threadIdx.x >> 6;         // 0..7 column-split wave id
  const int b  = blockIdx.x / 10;
  const int t0 = (blockIdx.x % 10) * 32;
  const int nst = steps[b];
  const bool active = (t0 < nst);          // block-uniform

  __shared__ float spart[CSPLIT][32];

  if (active) {
    const int lm = l & 15;
    const int q  = l >> 4;

    const unsigned short* xp0 = Xh + ((size_t)b * LMAXT + t0 + lm) * HD + q * 8;
    const h8 a00 = ldh8(xp0);
    const h8 a01 = ldh8(xp0 + 32);
    const h8 a10 = ldh8(xp0 + 16 * HD);
    const h8 a11 = ldh8(xp0 + 16 * HD + 32);

    float s[8];
#pragma unroll
    for (int i = 0; i < 8; ++i) s[i] = 0.f;

    const int ct0 = wv * 33;
    const int ct1 = (ct0 + 33 < NTILE) ? (ct0 + 33) : NTILE;   // wave 7: 26

    const unsigned short* wp = Wh + lm * 64 + q * 8;
    const float* bop = bo2 + lm;

    h8 b0 = ldh8(wp + (size_t)ct0 * 1024);
    h8 b1 = ldh8(wp + (size_t)ct0 * 1024 + 32);
    float bo = bop[ct0 * 16];
    for (int ct = ct0; ct < ct1; ++ct) {
      h8 nb0, nb1; float nbo;
      if (ct + 1 < ct1) {
        const unsigned short* wpn = wp + (size_t)(ct + 1) * 1024;
        nb0 = ldh8(wpn); nb1 = ldh8(wpn + 32); nbo = bop[(ct + 1) * 16];
      }
      f32x4 acc0 = {0.f, 0.f, 0.f, 0.f};
      f32x4 acc1 = {0.f, 0.f, 0.f, 0.f};
      acc0 = __builtin_amdgcn_mfma_f32_16x16x32_f16(a00, b0, acc0, 0, 0, 0);
      acc0 = __builtin_amdgcn_mfma_f32_16x16x32_f16(a01, b1, acc0, 0, 0, 0);
      acc1 = __builtin_amdgcn_mfma_f32_16x16x32_f16(a10, b0, acc1, 0, 0, 0);
      acc1 = __builtin_amdgcn_mfma_f32_16x16x32_f16(a11, b1, acc1, 0, 0, 0);
#pragma unroll
      for (int i = 0; i < 4; ++i) {
        s[i]     += ex2(fmaf(acc0[i], LOG2E, bo));
        s[4 + i] += ex2(fmaf(acc1[i], LOG2E, bo));
      }
      if (ct + 1 < ct1) { b0 = nb0; b1 = nb1; bo = nbo; }
    }

    // reduce across the 16 lanes (lm) sharing each row
#pragma unroll
    for (int m = 1; m < 16; m <<= 1) {
#pragma unroll
      for (int i = 0; i < 8; ++i) s[i] += __shfl_xor(s[i], m, 64);
    }
    // D-layout: lane holds rows q*4+i (tile0) / 16+q*4+i (tile1)
    if (lm == 0) {
#pragma unroll
      for (int i = 0; i < 4; ++i) {
        spart[wv][q * 4 + i]      = s[i];
        spart[wv][16 + q * 4 + i] = s[4 + i];
      }
    }
  }
  __syncthreads();

  float nll = 0.f;
  if (active && threadIdx.x < 32) {
    const int t = t0 + threadIdx.x;
    if (t < nst) {
      float ssum = 0.f;
#pragma unroll
      for (int c = 0; c < CSPLIT; ++c) ssum += spart[c][threadIdx.x];
      const int col = seq[b * SEQ_STRIDE + t + 1];
      // target logit from the SAME f16 operands (consistent cancellation)
      const unsigned short* xr = Xh + ((size_t)b * LMAXT + t) * HD;
      const unsigned short* wc = Wh + (size_t)(col >> 4) * 1024 + (col & 15) * 64;
      float tl = b_out[col];
#pragma unroll 16
      for (int k = 0; k < 64; ++k)
        tl = fmaf(h2f(xr[k]), h2f(wc[k]), tl);
      nll = (30.f + __logf(ssum)) - tl;
    }
  }
  if (threadIdx.x < 64) {
#pragma unroll
    for (int off = 32; off; off >>= 1) nll += __shfl_down(nll, off, 64);
    if (threadIdx.x == 0) {
      atomicAdd(loss_accum, nll);
      __threadfence();
      const unsigned old = atomicAdd(ticket, 1u);
      if (old == NBLK_PROJ - 1) {
        __threadfence();
        const float ls = atomicAdd(loss_accum, 0.f);   // coherent read
        int cnt = 0;
        for (int i = 0; i < NB; ++i) cnt += steps[i];
        out[0] = ls / (float)cnt;
      }
    }
  }
}

// ---------------------------------------------------------------------------
extern "C" void kernel_launch(void* const* d_in, const int* in_sizes, int n_in,
                              void* d_out, int out_size, void* d_ws,
                              size_t ws_size, hipStream_t stream) {
  const float* embeds  = (const float*)d_in[0];
  const float* true_fp = (const float*)d_in[1];
  const int*   perm    = (const int*)d_in[5];
  const float* W_ih    = (const float*)d_in[6];
  const float* b_ih    = (const float*)d_in[7];
  const float* W_hh    = (const float*)d_in[8];
  const float* b_hh    = (const float*)d_in[9];
  const float* W_out   = (const float*)d_in[10];
  const float* b_out   = (const float*)d_in[11];

  char*  ws     = (char*)d_ws;
  int*   seq    = (int*)(ws + SEQ_OFF);
  int*   steps  = (int*)(ws + STEPS_OFF);
  float* loss   = (float*)(ws + LOSS_OFF);
  unsigned* tick = (unsigned*)(ws + TICK_OFF);
  unsigned short* Xh = (unsigned short*)(ws + XB_OFF);
  unsigned short* Wh = (unsigned short*)(ws + WB_OFF);
  float* bo2    = (float*)(ws + BO_OFF);
  float* out    = (float*)d_out;

  k_front<<<NGRU + NTILE, 64, 0, stream>>>(
      embeds, true_fp, perm, W_ih, b_ih, W_hh, b_hh, W_out, b_out,
      seq, steps, Xh, Wh, bo2, loss, tick);
  k_proj<<<NBLK_PROJ, 512, 0, stream>>>(
      Xh, Wh, bo2, seq, steps, b_out, loss, tick, out);
}

// Round 12
// 280.114 us; speedup vs baseline: 1.4471x; 1.4471x over previous
//
#include <hip/hip_runtime.h>
#include <hip/hip_fp16.h>
#include <cstdint>
#include <cstddef>

// Problem constants (fixed by reference)
#define NB      64      // batch
#define NBITS   4096
#define HD      64      // hidden
#define IN_DIM  4098
#define LMAXT   320
#define SEQ_STRIDE 336  // padded seq row (>= LMAX+2, mult of 16)
#define NTILE   257     // col tiles of 16 (4112 padded cols)
#define LOG2E   1.44269504088896340f
#define TWO_L2E 2.88539008177792680f
#define CSPLIT  8       // column-split waves per k_proj block
#define NBLK_PROJ 640
#define NGRU    32      // GRU blocks (2 rows per block/wave)

// Workspace layout (bytes)
static constexpr size_t SEQ_OFF    = 0;                              // 86016
static constexpr size_t STEPS_OFF  = 86016;                          // 256
static constexpr size_t LOSS_OFF   = 86272;                          // 4
static constexpr size_t TICK_OFF   = 86400;                          // 4
static constexpr size_t XB_OFF     = 86528;                          // 64*320*64*2
static constexpr size_t WB_OFF     = XB_OFF + 2621440;               // 257*1024*2
static constexpr size_t BO_OFF     = WB_OFF + 526336;                // 4112*4

typedef float     f32x4  __attribute__((ext_vector_type(4)));
typedef _Float16  h2     __attribute__((ext_vector_type(2)));
typedef _Float16  h8     __attribute__((ext_vector_type(8)));

#if __has_builtin(__builtin_amdgcn_fdot2)
#define FDOT2(a, b, c) __builtin_amdgcn_fdot2((a), (b), (c), false)
#else
#define FDOT2(a, b, c) fmaf((float)(a)[0], (float)(b)[0], \
                        fmaf((float)(a)[1], (float)(b)[1], (c)))
#endif

// glibc's math.h macro-expands a declaration named __exp2f -> do NOT use that
// identifier; go straight to the HW builtin (v_exp_f32).
__device__ __forceinline__ float ex2(float x) {
#if __has_builtin(__builtin_amdgcn_exp2f)
  return __builtin_amdgcn_exp2f(x);
#else
  return __expf(x * 0.6931471805599453f);
#endif
}
__device__ __forceinline__ float frcp(float x) {
#if __has_builtin(__builtin_amdgcn_rcpf)
  return __builtin_amdgcn_rcpf(x);
#else
  return 1.f / x;
#endif
}

__device__ __forceinline__ unsigned short f2h(float f) {
  return __builtin_bit_cast(unsigned short, (_Float16)f);
}
__device__ __forceinline__ float h2f(unsigned short u) {
  return (float)__builtin_bit_cast(_Float16, u);
}
__device__ __forceinline__ h8 ldh8(const unsigned short* p) {
  return *(const h8*)p;
}
__device__ __forceinline__ void wave_lds_fence() {
  __asm__ __volatile__("s_waitcnt lgkmcnt(0)" ::: "memory");
}

// R8-verified parallel prefix-sum compaction for one batch row.
__device__ __forceinline__ int compact_row(
    int b, const float* __restrict__ true_fp, const int* __restrict__ perm,
    unsigned long long* bits, int* seqLrow, int* srow, int j) {
  {
    const float* row = true_fp + (size_t)b * NBITS;
    const float4* rv = (const float4*)(row + j * 64);
    unsigned long long w = 0ull;
#pragma unroll
    for (int i = 0; i < 16; ++i) {
      const float4 v = rv[i];
      w |= (unsigned long long)(v.x > 0.f) << (4 * i + 0);
      w |= (unsigned long long)(v.y > 0.f) << (4 * i + 1);
      w |= (unsigned long long)(v.z > 0.f) << (4 * i + 2);
      w |= (unsigned long long)(v.w > 0.f) << (4 * i + 3);
    }
    bits[j] = w;
  }
  wave_lds_fence();

  unsigned long long m = 0ull;
  {
    const int4* pv = (const int4*)(perm + j * 64);
#pragma unroll
    for (int q4 = 0; q4 < 16; ++q4) {
      const int4 p4 = pv[q4];
      m |= (unsigned long long)((bits[p4.x >> 6] >> (p4.x & 63)) & 1ull) << (4 * q4 + 0);
      m |= (unsigned long long)((bits[p4.y >> 6] >> (p4.y & 63)) & 1ull) << (4 * q4 + 1);
      m |= (unsigned long long)((bits[p4.z >> 6] >> (p4.z & 63)) & 1ull) << (4 * q4 + 2);
      m |= (unsigned long long)((bits[p4.w >> 6] >> (p4.w & 63)) & 1ull) << (4 * q4 + 3);
    }
  }
  const int cnt = __popcll(m);
  int incl = cnt;
#pragma unroll
  for (int d = 1; d < 64; d <<= 1) {
    const int v = __shfl_up(incl, d, 64);
    if (j >= d) incl += v;
  }
  const int S = __shfl(incl, 63, 64);
  if (j == 0) { srow[0] = 0; seqLrow[0] = 0; }
  {
    int idx = 1 + (incl - cnt);
    unsigned long long mm = m;
    while (mm) {
      const int i = __builtin_ctzll(mm);
      mm &= mm - 1;
      if (idx <= LMAXT) {
        const int col = j * 64 + 1 + i;
        srow[idx] = col; seqLrow[idx] = col;
      }
      ++idx;
    }
  }
  if (j == 63) {
    const int last = 1 + S;
    if (last <= LMAXT) { srow[last] = IN_DIM - 1; seqLrow[last] = IN_DIM - 1; }
  }
  const int base = S + 2;
  const int cap = (base <= LMAXT + 1) ? base : (LMAXT + 1);
  for (int i = cap + j; i < SEQ_STRIDE; i += 64) srow[i] = 0;
  for (int i = cap + j; i < LMAXT + 2; i += 64) seqLrow[i] = 0;
  int nst = S + 1;
  if (nst > LMAXT) nst = LMAXT;
  return nst;
}

// ---------------------------------------------------------------------------
// Kernel FRONT. R10 post-mortem: fine-grained A/B dot interleave + depth-4
// prefetch put peak live regs ~175 -> hot-loop scratch spill (VALUBusy
// 3.4->1.0%, 3.5x). This version cuts peak pressure: (a) row A's full DOT8
// sequence THEN row B's (one row's h8/temps live at a time; B's issue stream
// still hides A's chain tails/epilogue), (b) prefetch depth 2 per row
// (lookahead ~1800cyc >> L2 latency). Peak-live est ~152 < 168 granted.
// Math identical to R10 (absmax 0 verified).
// ---------------------------------------------------------------------------
#define W_DEF(i) h2 wr##i, wz##i, wn##i;
#define W_INIT(i) {                                                  \
    const float* w0_ = W_hh + (size_t)(2 * (i)) * 192;               \
    const float* w1_ = W_hh + (size_t)(2 * (i) + 1) * 192;           \
    wr##i[0] = (_Float16)w0_[g];       wr##i[1] = (_Float16)w1_[g];  \
    wz##i[0] = (_Float16)w0_[64 + g];  wz##i[1] = (_Float16)w1_[64 + g]; \
    wn##i[0] = (_Float16)w0_[128 + g]; wn##i[1] = (_Float16)w1_[128 + g]; }

#define W_ALIAS(i8, a, b, c, d)                                           \
  const h2 wr##i8##_0 = wr##a, wr##i8##_1 = wr##b,                        \
           wr##i8##_2 = wr##c, wr##i8##_3 = wr##d;                        \
  const h2 wz##i8##_0 = wz##a, wz##i8##_1 = wz##b,                        \
           wz##i8##_2 = wz##c, wz##i8##_3 = wz##d;                        \
  const h2 wn##i8##_0 = wn##a, wn##i8##_1 = wn##b,                        \
           wn##i8##_2 = wn##c, wn##i8##_3 = wn##d;

// One 8-elem dot-group for one row; accumulator prefix P in {A,B}.
#define DOT8R(i, hp, P) {                                                 \
    const h8 v_ = hp[i];                                                  \
    const h2 e0_ = __builtin_shufflevector(v_, v_, 0, 1);                 \
    const h2 e1_ = __builtin_shufflevector(v_, v_, 2, 3);                 \
    const h2 e2_ = __builtin_shufflevector(v_, v_, 4, 5);                 \
    const h2 e3_ = __builtin_shufflevector(v_, v_, 6, 7);                 \
    P##r0 = FDOT2(e0_, wr##i##_0, P##r0);  P##r1 = FDOT2(e1_, wr##i##_1, P##r1); \
    P##r0 = FDOT2(e2_, wr##i##_2, P##r0);  P##r1 = FDOT2(e3_, wr##i##_3, P##r1); \
    P##z0 = FDOT2(e0_, wz##i##_0, P##z0);  P##z1 = FDOT2(e1_, wz##i##_1, P##z1); \
    P##z0 = FDOT2(e2_, wz##i##_2, P##z0);  P##z1 = FDOT2(e3_, wz##i##_3, P##z1); \
    P##n0 = FDOT2(e0_, wn##i##_0, P##n0);  P##n1 = FDOT2(e1_, wn##i##_1, P##n1); \
    P##n0 = FDOT2(e2_, wn##i##_2, P##n0);  P##n1 = FDOT2(e3_, wn##i##_3, P##n1); }

__global__ __launch_bounds__(64)
__attribute__((amdgpu_waves_per_eu(1, 1)))
void k_front(
    const float* __restrict__ embeds,
    const float* __restrict__ true_fp, const int* __restrict__ perm,
    const float* __restrict__ W_ih, const float* __restrict__ b_ih,
    const float* __restrict__ W_hh, const float* __restrict__ b_hh,
    const float* __restrict__ W_out, const float* __restrict__ b_out,
    int* __restrict__ seq, int* __restrict__ steps,
    unsigned short* __restrict__ Xh,
    unsigned short* __restrict__ Wh, float* __restrict__ bo2,
    float* __restrict__ loss_accum, unsigned* __restrict__ ticket) {
  const int blk = blockIdx.x;

  if (blk >= NGRU) {
    // ---- W tile prep for col tile c (R2/R9-verified 64-thread variant) ----
    const int c = blk - NGRU;            // 0..256
    const int t = threadIdx.x;           // 0..63
    if (c == 0 && t == 0) { *loss_accum = 0.f; *ticket = 0u; }
    const int m = t & 15;                // col within tile
    const int col = c * 16 + m;
    const bool cok = col < IN_DIM;
#pragma unroll
    for (int kp = 0; kp < 16; ++kp) {
      const int k = kp * 4 + (t >> 4);
      const float v = cok ? W_out[(size_t)k * IN_DIM + col] : 0.f;
      Wh[c * 1024 + m * 64 + k] = f2h(v);
    }
    if (t < 16) {
      const int cc = c * 16 + t;
      bo2[c * 16 + t] = (cc < IN_DIM) ? (b_out[cc] - 30.f) * LOG2E : -1e30f;
    }
    return;
  }

  // ---------------- blocks 0..31: 2-row compaction + GRU ----------------
  const int bA = 2 * blk;
  const int bB = 2 * blk + 1;
  const int g = threadIdx.x;   // 0..63
  const int j = g;

  __shared__ unsigned long long bits[64];
  __shared__ __align__(16) _Float16 hlA[HD];
  __shared__ __align__(16) _Float16 hlB[HD];
  __shared__ int seqLA[LMAXT + 2];
  __shared__ int seqLB[LMAXT + 2];

  // Issue the scattered W_hh register loads FIRST; latency hides under the
  // compaction (R7/R8-verified pattern).
  W_DEF(0)  W_DEF(1)  W_DEF(2)  W_DEF(3)  W_DEF(4)  W_DEF(5)  W_DEF(6)  W_DEF(7)
  W_DEF(8)  W_DEF(9)  W_DEF(10) W_DEF(11) W_DEF(12) W_DEF(13) W_DEF(14) W_DEF(15)
  W_DEF(16) W_DEF(17) W_DEF(18) W_DEF(19) W_DEF(20) W_DEF(21) W_DEF(22) W_DEF(23)
  W_DEF(24) W_DEF(25) W_DEF(26) W_DEF(27) W_DEF(28) W_DEF(29) W_DEF(30) W_DEF(31)
  W_INIT(0)  W_INIT(1)  W_INIT(2)  W_INIT(3)  W_INIT(4)  W_INIT(5)  W_INIT(6)  W_INIT(7)
  W_INIT(8)  W_INIT(9)  W_INIT(10) W_INIT(11) W_INIT(12) W_INIT(13) W_INIT(14) W_INIT(15)
  W_INIT(16) W_INIT(17) W_INIT(18) W_INIT(19) W_INIT(20) W_INIT(21) W_INIT(22) W_INIT(23)
  W_INIT(24) W_INIT(25) W_INIT(26) W_INIT(27) W_INIT(28) W_INIT(29) W_INIT(30) W_INIT(31)
  W_ALIAS(0, 0, 1, 2, 3)     W_ALIAS(1, 4, 5, 6, 7)
  W_ALIAS(2, 8, 9, 10, 11)   W_ALIAS(3, 12, 13, 14, 15)
  W_ALIAS(4, 16, 17, 18, 19) W_ALIAS(5, 20, 21, 22, 23)
  W_ALIAS(6, 24, 25, 26, 27) W_ALIAS(7, 28, 29, 30, 31)

  const float br2  = (b_ih[g]       + b_hh[g])       * -LOG2E;
  const float bz2  = (b_ih[64 + g]  + b_hh[64 + g])  * -LOG2E;
  const float bn2  = b_ih[128 + g]  * TWO_L2E;
  const float bhn2 = b_hh[128 + g]  * TWO_L2E;

  // ---- compaction for both rows (single wave, lockstep -> no race) ----
  const int nstA = compact_row(bA, true_fp, perm, bits,
                               seqLA, seq + bA * SEQ_STRIDE, j);
  wave_lds_fence();
  const int nstB = compact_row(bB, true_fp, perm, bits,
                               seqLB, seq + bB * SEQ_STRIDE, j);
  if (j == 0) { steps[bA] = nstA; steps[bB] = nstB; }
  wave_lds_fence();

  // ---- 2-row GRU recurrence ----
  float hselfA = embeds[bA * HD + g];
  float hselfB = embeds[bB * HD + g];
  hlA[g] = (_Float16)hselfA;
  hlB[g] = (_Float16)hselfB;

  unsigned short* xptrA = Xh + (size_t)bA * LMAXT * HD + g;
  unsigned short* xptrB = Xh + (size_t)bB * LMAXT * HD + g;

  // depth-2 prefetch slots, both rows (12 regs; R10's depth-4x2 = 24 spilled)
  float pA0r, pA0z, pA0n, pA1r, pA1z, pA1n;
  float pB0r, pB0z, pB0n, pB1r, pB1z, pB1n;
#define PF_INIT(P, SL, k)                                                  \
  { const float* r_ = W_ih + (size_t)SL[k] * 192;                          \
    P##k##r = fmaf(r_[g], -LOG2E, br2);                                    \
    P##k##z = fmaf(r_[64 + g], -LOG2E, bz2);                               \
    P##k##n = fmaf(r_[128 + g], TWO_L2E, bn2); }
  PF_INIT(pA, seqLA, 0) PF_INIT(pA, seqLA, 1)
  PF_INIT(pB, seqLB, 0) PF_INIT(pB, seqLB, 1)
#undef PF_INIT

#define GSTEP2(u) {                                                       \
    int nt_ = t + (u) + 2; nt_ = (nt_ <= LMAXT + 1) ? nt_ : (LMAXT + 1);  \
    const int sidxA_ = seqLA[nt_];                                        \
    const int sidxB_ = seqLB[nt_];                                        \
    const h8* hpA = (const h8*)hlA;                                       \
    const h8* hpB = (const h8*)hlB;                                       \
    float Ar0=0.f, Ar1=0.f, Az0=0.f, Az1=0.f, An0=0.f, An1=0.f;           \
    DOT8R(0, hpA, A) DOT8R(1, hpA, A) DOT8R(2, hpA, A) DOT8R(3, hpA, A)   \
    DOT8R(4, hpA, A) DOT8R(5, hpA, A) DOT8R(6, hpA, A) DOT8R(7, hpA, A)   \
    float Br0=0.f, Br1=0.f, Bz0=0.f, Bz1=0.f, Bn0=0.f, Bn1=0.f;           \
    DOT8R(0, hpB, B) DOT8R(1, hpB, B) DOT8R(2, hpB, B) DOT8R(3, hpB, B)   \
    DOT8R(4, hpB, B) DOT8R(5, hpB, B) DOT8R(6, hpB, B) DOT8R(7, hpB, B)   \
    const float rrA = frcp(1.f + ex2(fmaf(Ar0 + Ar1, -LOG2E, pA##u##r))); \
    const float zzA = frcp(1.f + ex2(fmaf(Az0 + Az1, -LOG2E, pA##u##z))); \
    const float g2A = fmaf(An0 + An1, TWO_L2E, bhn2);                     \
    const float qA  = frcp(1.f + ex2(fmaf(rrA, g2A, pA##u##n)));          \
    const float thA = fmaf(-2.f, qA, 1.f);                                \
    const float hnA = fmaf(zzA, hselfA - thA, thA);                       \
    const float rrB = frcp(1.f + ex2(fmaf(Br0 + Br1, -LOG2E, pB##u##r))); \
    const float zzB = frcp(1.f + ex2(fmaf(Bz0 + Bz1, -LOG2E, pB##u##z))); \
    const float g2B = fmaf(Bn0 + Bn1, TWO_L2E, bhn2);                     \
    const float qB  = frcp(1.f + ex2(fmaf(rrB, g2B, pB##u##n)));          \
    const float thB = fmaf(-2.f, qB, 1.f);                                \
    const float hnB = fmaf(zzB, hselfB - thB, thB);                       \
    hselfA = hnA; hselfB = hnB;                                           \
    const _Float16 hhA = (_Float16)hnA;                                   \
    const _Float16 hhB = (_Float16)hnB;                                   \
    hlA[g] = hhA; hlB[g] = hhB;                                           \
    xptrA[(size_t)(t + (u)) * HD] = __builtin_bit_cast(unsigned short, hhA);\
    xptrB[(size_t)(t + (u)) * HD] = __builtin_bit_cast(unsigned short, hhB);\
    const float* rwA_ = W_ih + (size_t)sidxA_ * 192;                      \
    pA##u##r = fmaf(rwA_[g], -LOG2E, br2);                                \
    pA##u##z = fmaf(rwA_[64 + g], -LOG2E, bz2);                           \
    pA##u##n = fmaf(rwA_[128 + g], TWO_L2E, bn2);                         \
    const float* rwB_ = W_ih + (size_t)sidxB_ * 192;                      \
    pB##u##r = fmaf(rwB_[g], -LOG2E, br2);                                \
    pB##u##z = fmaf(rwB_[64 + g], -LOG2E, bz2);                           \
    pB##u##n = fmaf(rwB_[128 + g], TWO_L2E, bn2); }

  const int nstMax = (nstA > nstB) ? nstA : nstB;
  const int ngroups = (nstMax + 1) >> 1;
  for (int tg = 0; tg < ngroups; ++tg) {
    const int t = tg * 2;
    GSTEP2(0)
    GSTEP2(1)
  }
#undef GSTEP2

  // zero-fill padded rows for both batch rows (overwrites garbage tail
  // stores, including the short row's overshoot steps).
  {
    uint4 z4; z4.x = 0u; z4.y = 0u; z4.z = 0u; z4.w = 0u;
    uint4* xzA = (uint4*)(Xh + (size_t)bA * (LMAXT * HD) + (size_t)nstA * HD);
    const int n4A = (LMAXT - nstA) * 8;
    for (int i = g; i < n4A; i += 64) xzA[i] = z4;
    uint4* xzB = (uint4*)(Xh + (size_t)bB * (LMAXT * HD) + (size_t)nstB * HD);
    const int n4B = (LMAXT - nstB) * 8;
    for (int i = g; i < n4B; i += 64) xzB[i] = z4;
  }
}

// ---------------------------------------------------------------------------
// Kernel C: MFMA f16 fused projection + logsumexp + NLL.
// Finalize folded in via device-scope atomic ticket (R2-verified).
// ---------------------------------------------------------------------------
__global__ __launch_bounds__(512)
__attribute__((amdgpu_waves_per_eu(4, 8)))
void k_proj(
    const unsigned short* __restrict__ Xh,
    const unsigned short* __restrict__ Wh,
    const float* __restrict__ bo2,
    const int* __restrict__ seq, const int* __restrict__ steps,
    const float* __restrict__ b_out,
    float* __restrict__ loss_accum, unsigned* __restrict__ ticket,
    float* __restrict__ out) {
  const int l  = threadIdx.x & 63;
  const int wv = threadIdx.x >> 6;         // 0..7 column-split wave id
  const int b  = blockIdx.x / 10;
  const int t0 = (blockIdx.x % 10) * 32;
  const int nst = steps[b];
  const bool active = (t0 < nst);          // block-uniform

  __shared__ float spart[CSPLIT][32];

  if (active) {
    const int lm = l & 15;
    const int q  = l >> 4;

    const unsigned short* xp0 = Xh + ((size_t)b * LMAXT + t0 + lm) * HD + q * 8;
    const h8 a00 = ldh8(xp0);
    const h8 a01 = ldh8(xp0 + 32);
    const h8 a10 = ldh8(xp0 + 16 * HD);
    const h8 a11 = ldh8(xp0 + 16 * HD + 32);

    float s[8];
#pragma unroll
    for (int i = 0; i < 8; ++i) s[i] = 0.f;

    const int ct0 = wv * 33;
    const int ct1 = (ct0 + 33 < NTILE) ? (ct0 + 33) : NTILE;   // wave 7: 26

    const unsigned short* wp = Wh + lm * 64 + q * 8;
    const float* bop = bo2 + lm;

    h8 b0 = ldh8(wp + (size_t)ct0 * 1024);
    h8 b1 = ldh8(wp + (size_t)ct0 * 1024 + 32);
    float bo = bop[ct0 * 16];
    for (int ct = ct0; ct < ct1; ++ct) {
      h8 nb0, nb1; float nbo;
      if (ct + 1 < ct1) {
        const unsigned short* wpn = wp + (size_t)(ct + 1) * 1024;
        nb0 = ldh8(wpn); nb1 = ldh8(wpn + 32); nbo = bop[(ct + 1) * 16];
      }
      f32x4 acc0 = {0.f, 0.f, 0.f, 0.f};
      f32x4 acc1 = {0.f, 0.f, 0.f, 0.f};
      acc0 = __builtin_amdgcn_mfma_f32_16x16x32_f16(a00, b0, acc0, 0, 0, 0);
      acc0 = __builtin_amdgcn_mfma_f32_16x16x32_f16(a01, b1, acc0, 0, 0, 0);
      acc1 = __builtin_amdgcn_mfma_f32_16x16x32_f16(a10, b0, acc1, 0, 0, 0);
      acc1 = __builtin_amdgcn_mfma_f32_16x16x32_f16(a11, b1, acc1, 0, 0, 0);
#pragma unroll
      for (int i = 0; i < 4; ++i) {
        s[i]     += ex2(fmaf(acc0[i], LOG2E, bo));
        s[4 + i] += ex2(fmaf(acc1[i], LOG2E, bo));
      }
      if (ct + 1 < ct1) { b0 = nb0; b1 = nb1; bo = nbo; }
    }

    // reduce across the 16 lanes (lm) sharing each row
#pragma unroll
    for (int m = 1; m < 16; m <<= 1) {
#pragma unroll
      for (int i = 0; i < 8; ++i) s[i] += __shfl_xor(s[i], m, 64);
    }
    // D-layout: lane holds rows q*4+i (tile0) / 16+q*4+i (tile1)
    if (lm == 0) {
#pragma unroll
      for (int i = 0; i < 4; ++i) {
        spart[wv][q * 4 + i]      = s[i];
        spart[wv][16 + q * 4 + i] = s[4 + i];
      }
    }
  }
  __syncthreads();

  float nll = 0.f;
  if (active && threadIdx.x < 32) {
    const int t = t0 + threadIdx.x;
    if (t < nst) {
      float ssum = 0.f;
#pragma unroll
      for (int c = 0; c < CSPLIT; ++c) ssum += spart[c][threadIdx.x];
      const int col = seq[b * SEQ_STRIDE + t + 1];
      // target logit from the SAME f16 operands (consistent cancellation)
      const unsigned short* xr = Xh + ((size_t)b * LMAXT + t) * HD;
      const unsigned short* wc = Wh + (size_t)(col >> 4) * 1024 + (col & 15) * 64;
      float tl = b_out[col];
#pragma unroll 16
      for (int k = 0; k < 64; ++k)
        tl = fmaf(h2f(xr[k]), h2f(wc[k]), tl);
      nll = (30.f + __logf(ssum)) - tl;
    }
  }
  if (threadIdx.x < 64) {
#pragma unroll
    for (int off = 32; off; off >>= 1) nll += __shfl_down(nll, off, 64);
    if (threadIdx.x == 0) {
      atomicAdd(loss_accum, nll);
      __threadfence();
      const unsigned old = atomicAdd(ticket, 1u);
      if (old == NBLK_PROJ - 1) {
        __threadfence();
        const float ls = atomicAdd(loss_accum, 0.f);   // coherent read
        int cnt = 0;
        for (int i = 0; i < NB; ++i) cnt += steps[i];
        out[0] = ls / (float)cnt;
      }
    }
  }
}

// ---------------------------------------------------------------------------
extern "C" void kernel_launch(void* const* d_in, const int* in_sizes, int n_in,
                              void* d_out, int out_size, void* d_ws,
                              size_t ws_size, hipStream_t stream) {
  const float* embeds  = (const float*)d_in[0];
  const float* true_fp = (const float*)d_in[1];
  const int*   perm    = (const int*)d_in[5];
  const float* W_ih    = (const float*)d_in[6];
  const float* b_ih    = (const float*)d_in[7];
  const float* W_hh    = (const float*)d_in[8];
  const float* b_hh    = (const float*)d_in[9];
  const float* W_out   = (const float*)d_in[10];
  const float* b_out   = (const float*)d_in[11];

  char*  ws     = (char*)d_ws;
  int*   seq    = (int*)(ws + SEQ_OFF);
  int*   steps  = (int*)(ws + STEPS_OFF);
  float* loss   = (float*)(ws + LOSS_OFF);
  unsigned* tick = (unsigned*)(ws + TICK_OFF);
  unsigned short* Xh = (unsigned short*)(ws + XB_OFF);
  unsigned short* Wh = (unsigned short*)(ws + WB_OFF);
  float* bo2    = (float*)(ws + BO_OFF);
  float* out    = (float*)d_out;

  k_front<<<NGRU + NTILE, 64, 0, stream>>>(
      embeds, true_fp, perm, W_ih, b_ih, W_hh, b_hh, W_out, b_out,
      seq, steps, Xh, Wh, bo2, loss, tick);
  k_proj<<<NBLK_PROJ, 512, 0, stream>>>(
      Xh, Wh, bo2, seq, steps, b_out, loss, tick, out);
}

// Round 13
// 210.107 us; speedup vs baseline: 1.9293x; 1.3332x over previous
//
#include <hip/hip_runtime.h>
#include <hip/hip_fp16.h>
#include <cstdint>
#include <cstddef>

// Problem constants (fixed by reference)
#define NB      64      // batch
#define NBITS   4096
#define HD      64      // hidden
#define IN_DIM  4098
#define LMAXT   320
#define SEQ_STRIDE 336  // padded seq row (>= LMAX+2, mult of 16)
#define NTILE   257     // col tiles of 16 (4112 padded cols)
#define LOG2E   1.44269504088896340f
#define TWO_L2E 2.88539008177792680f
#define CSPLIT  8       // column-split waves per k_proj block
#define NBLK_PROJ 640

// Workspace layout (bytes)
static constexpr size_t SEQ_OFF    = 0;                              // 86016
static constexpr size_t STEPS_OFF  = 86016;                          // 256
static constexpr size_t LOSS_OFF   = 86272;                          // 4
static constexpr size_t TICK_OFF   = 86400;                          // 4
static constexpr size_t XB_OFF     = 86528;                          // 64*320*64*2
static constexpr size_t WB_OFF     = XB_OFF + 2621440;               // 257*1024*2
static constexpr size_t BO_OFF     = WB_OFF + 526336;                // 4112*4

typedef float     f32x4  __attribute__((ext_vector_type(4)));
typedef _Float16  h2     __attribute__((ext_vector_type(2)));
typedef _Float16  h8     __attribute__((ext_vector_type(8)));

#if __has_builtin(__builtin_amdgcn_fdot2)
#define FDOT2(a, b, c) __builtin_amdgcn_fdot2((a), (b), (c), false)
#else
#define FDOT2(a, b, c) fmaf((float)(a)[0], (float)(b)[0], \
                        fmaf((float)(a)[1], (float)(b)[1], (c)))
#endif

// glibc's math.h macro-expands a declaration named __exp2f -> do NOT use that
// identifier; go straight to the HW builtin (v_exp_f32).
__device__ __forceinline__ float ex2(float x) {
#if __has_builtin(__builtin_amdgcn_exp2f)
  return __builtin_amdgcn_exp2f(x);
#else
  return __expf(x * 0.6931471805599453f);
#endif
}
__device__ __forceinline__ float frcp(float x) {
#if __has_builtin(__builtin_amdgcn_rcpf)
  return __builtin_amdgcn_rcpf(x);
#else
  return 1.f / x;
#endif
}

__device__ __forceinline__ unsigned short f2h(float f) {
  return __builtin_bit_cast(unsigned short, (_Float16)f);
}
__device__ __forceinline__ float h2f(unsigned short u) {
  return (float)__builtin_bit_cast(_Float16, u);
}
__device__ __forceinline__ h8 ldh8(const unsigned short* p) {
  return *(const h8*)p;
}
__device__ __forceinline__ void wave_lds_fence() {
  __asm__ __volatile__("s_waitcnt lgkmcnt(0)" ::: "memory");
}

// ---------------------------------------------------------------------------
// Kernel FRONT (R9 structure — best verified 211.4us):
//   blocks 0..63   : parallel-prefix compaction (R8) + single-row GRU.
//   blocks 64..320 : W_out f16 tile prep + loss/ticket zeroing.
// R10/R12 post-mortem: 2-row ILP spills at every interleave granularity
// (VGPR 168 granted but peak-live exceeds it; VALUBusy 3.4->2.0, 1.9x) —
// single-row is the structure. NEW in this round (within-step only): hoist
// the 3 W_ih prefetch loads to the TOP of GSTEP so the ~400cyc DOT8 block
// covers their L2 latency; fmas stay at the bottom (R3's cross-step variant
// regressed; this keeps slot structure and cross-step state identical).
// ---------------------------------------------------------------------------
#define W_DEF(i) h2 wr##i, wz##i, wn##i;
#define W_INIT(i) {                                                  \
    const float* w0_ = W_hh + (size_t)(2 * (i)) * 192;               \
    const float* w1_ = W_hh + (size_t)(2 * (i) + 1) * 192;           \
    wr##i[0] = (_Float16)w0_[g];       wr##i[1] = (_Float16)w1_[g];  \
    wz##i[0] = (_Float16)w0_[64 + g];  wz##i[1] = (_Float16)w1_[64 + g]; \
    wn##i[0] = (_Float16)w0_[128 + g]; wn##i[1] = (_Float16)w1_[128 + g]; }

#define DOT8(i) {                                                         \
    const h8 v_ = hp8[i];                                                 \
    const h2 e0_ = __builtin_shufflevector(v_, v_, 0, 1);                 \
    const h2 e1_ = __builtin_shufflevector(v_, v_, 2, 3);                 \
    const h2 e2_ = __builtin_shufflevector(v_, v_, 4, 5);                 \
    const h2 e3_ = __builtin_shufflevector(v_, v_, 6, 7);                 \
    sr0 = FDOT2(e0_, wr##i##_0, sr0);  sr1 = FDOT2(e1_, wr##i##_1, sr1);  \
    sr0 = FDOT2(e2_, wr##i##_2, sr0);  sr1 = FDOT2(e3_, wr##i##_3, sr1);  \
    sz0 = FDOT2(e0_, wz##i##_0, sz0);  sz1 = FDOT2(e1_, wz##i##_1, sz1);  \
    sz0 = FDOT2(e2_, wz##i##_2, sz0);  sz1 = FDOT2(e3_, wz##i##_3, sz1);  \
    sn0 = FDOT2(e0_, wn##i##_0, sn0);  sn1 = FDOT2(e1_, wn##i##_1, sn1);  \
    sn0 = FDOT2(e2_, wn##i##_2, sn0);  sn1 = FDOT2(e3_, wn##i##_3, sn1); }

#define W_ALIAS(i8, a, b, c, d)                                           \
  const h2 wr##i8##_0 = wr##a, wr##i8##_1 = wr##b,                        \
           wr##i8##_2 = wr##c, wr##i8##_3 = wr##d;                        \
  const h2 wz##i8##_0 = wz##a, wz##i8##_1 = wz##b,                        \
           wz##i8##_2 = wz##c, wz##i8##_3 = wz##d;                        \
  const h2 wn##i8##_0 = wn##a, wn##i8##_1 = wn##b,                        \
           wn##i8##_2 = wn##c, wn##i8##_3 = wn##d;

__global__ __launch_bounds__(64)
__attribute__((amdgpu_waves_per_eu(1, 1)))
void k_front(
    const float* __restrict__ embeds,
    const float* __restrict__ true_fp, const int* __restrict__ perm,
    const float* __restrict__ W_ih, const float* __restrict__ b_ih,
    const float* __restrict__ W_hh, const float* __restrict__ b_hh,
    const float* __restrict__ W_out, const float* __restrict__ b_out,
    int* __restrict__ seq, int* __restrict__ steps,
    unsigned short* __restrict__ Xh,
    unsigned short* __restrict__ Wh, float* __restrict__ bo2,
    float* __restrict__ loss_accum, unsigned* __restrict__ ticket) {
  const int blk = blockIdx.x;

  if (blk >= NB) {
    // ---- W tile prep for col tile c (R2/R9-verified 64-thread variant) ----
    const int c = blk - NB;              // 0..256
    const int t = threadIdx.x;           // 0..63
    if (c == 0 && t == 0) { *loss_accum = 0.f; *ticket = 0u; }
    const int m = t & 15;                // col within tile
    const int col = c * 16 + m;
    const bool cok = col < IN_DIM;
#pragma unroll
    for (int kp = 0; kp < 16; ++kp) {
      const int k = kp * 4 + (t >> 4);
      const float v = cok ? W_out[(size_t)k * IN_DIM + col] : 0.f;
      Wh[c * 1024 + m * 64 + k] = f2h(v);
    }
    if (t < 16) {
      const int cc = c * 16 + t;
      bo2[c * 16 + t] = (cc < IN_DIM) ? (b_out[cc] - 30.f) * LOG2E : -1e30f;
    }
    return;
  }

  // ------------------- blocks 0..63: compaction + GRU -------------------
  const int b = blk;
  const int g = threadIdx.x;   // 0..63

  __shared__ unsigned long long bits[64];
  __shared__ __align__(16) _Float16 hl[HD];
  __shared__ int seqL[LMAXT + 2];

  // Issue the scattered W_hh register loads FIRST; latency hides under the
  // compaction below (R2/R7/R8/R9-verified: VGPR stays 132).
  W_DEF(0)  W_DEF(1)  W_DEF(2)  W_DEF(3)  W_DEF(4)  W_DEF(5)  W_DEF(6)  W_DEF(7)
  W_DEF(8)  W_DEF(9)  W_DEF(10) W_DEF(11) W_DEF(12) W_DEF(13) W_DEF(14) W_DEF(15)
  W_DEF(16) W_DEF(17) W_DEF(18) W_DEF(19) W_DEF(20) W_DEF(21) W_DEF(22) W_DEF(23)
  W_DEF(24) W_DEF(25) W_DEF(26) W_DEF(27) W_DEF(28) W_DEF(29) W_DEF(30) W_DEF(31)
  W_INIT(0)  W_INIT(1)  W_INIT(2)  W_INIT(3)  W_INIT(4)  W_INIT(5)  W_INIT(6)  W_INIT(7)
  W_INIT(8)  W_INIT(9)  W_INIT(10) W_INIT(11) W_INIT(12) W_INIT(13) W_INIT(14) W_INIT(15)
  W_INIT(16) W_INIT(17) W_INIT(18) W_INIT(19) W_INIT(20) W_INIT(21) W_INIT(22) W_INIT(23)
  W_INIT(24) W_INIT(25) W_INIT(26) W_INIT(27) W_INIT(28) W_INIT(29) W_INIT(30) W_INIT(31)
  W_ALIAS(0, 0, 1, 2, 3)     W_ALIAS(1, 4, 5, 6, 7)
  W_ALIAS(2, 8, 9, 10, 11)   W_ALIAS(3, 12, 13, 14, 15)
  W_ALIAS(4, 16, 17, 18, 19) W_ALIAS(5, 20, 21, 22, 23)
  W_ALIAS(6, 24, 25, 26, 27) W_ALIAS(7, 28, 29, 30, 31)

  const float br2  = (b_ih[g]       + b_hh[g])       * -LOG2E;
  const float bz2  = (b_ih[64 + g]  + b_hh[64 + g])  * -LOG2E;
  const float bn2  = b_ih[128 + g]  * TWO_L2E;
  const float bhn2 = b_hh[128 + g]  * TWO_L2E;

  // ---- compaction: parallel prefix-sum (R8-verified) ----
  const int j = g;
  {
    const float* row = true_fp + (size_t)b * NBITS;
    const float4* rv = (const float4*)(row + j * 64);
    unsigned long long w = 0ull;
#pragma unroll
    for (int i = 0; i < 16; ++i) {
      const float4 v = rv[i];
      w |= (unsigned long long)(v.x > 0.f) << (4 * i + 0);
      w |= (unsigned long long)(v.y > 0.f) << (4 * i + 1);
      w |= (unsigned long long)(v.z > 0.f) << (4 * i + 2);
      w |= (unsigned long long)(v.w > 0.f) << (4 * i + 3);
    }
    bits[j] = w;
  }
  wave_lds_fence();

  int* srow = seq + b * SEQ_STRIDE;

  // lane j owns cols j*64+1 .. j*64+64  ->  perm indices j*64 .. j*64+63
  unsigned long long m = 0ull;
  {
    const int4* pv = (const int4*)(perm + j * 64);
#pragma unroll
    for (int q4 = 0; q4 < 16; ++q4) {
      const int4 p4 = pv[q4];
      m |= (unsigned long long)((bits[p4.x >> 6] >> (p4.x & 63)) & 1ull) << (4 * q4 + 0);
      m |= (unsigned long long)((bits[p4.y >> 6] >> (p4.y & 63)) & 1ull) << (4 * q4 + 1);
      m |= (unsigned long long)((bits[p4.z >> 6] >> (p4.z & 63)) & 1ull) << (4 * q4 + 2);
      m |= (unsigned long long)((bits[p4.w >> 6] >> (p4.w & 63)) & 1ull) << (4 * q4 + 3);
    }
  }
  const int cnt = __popcll(m);
  int incl = cnt;
#pragma unroll
  for (int d = 1; d < 64; d <<= 1) {
    const int v = __shfl_up(incl, d, 64);
    if (j >= d) incl += v;
  }
  const int S = __shfl(incl, 63, 64);   // total set bits over cols 1..4096
  if (j == 0) { srow[0] = 0; seqL[0] = 0; }       // forced col 0
  {
    int idx = 1 + (incl - cnt);                   // exclusive prefix + 1
    unsigned long long mm = m;
    while (mm) {
      const int i = __builtin_ctzll(mm);
      mm &= mm - 1;
      if (idx <= LMAXT) {
        const int col = j * 64 + 1 + i;
        srow[idx] = col; seqL[idx] = col;
      }
      ++idx;
    }
  }
  if (j == 63) {                                  // forced col IN_DIM-1
    const int last = 1 + S;
    if (last <= LMAXT) { srow[last] = IN_DIM - 1; seqL[last] = IN_DIM - 1; }
  }
  const int base = S + 2;
  const int cap = (base <= LMAXT + 1) ? base : (LMAXT + 1);
  for (int i = cap + j; i < SEQ_STRIDE; i += 64) srow[i] = 0;
  for (int i = cap + j; i < LMAXT + 2; i += 64) seqL[i] = 0;
  int nst = S + 1;
  if (nst > LMAXT) nst = LMAXT;
  if (j == 0) steps[b] = nst;
  wave_lds_fence();

  // ---- GRU recurrence (R1 form; loads hoisted to top of step) ----
  float hself = embeds[b * HD + g];
  hl[g] = (_Float16)hself;

  unsigned short* xptr = Xh + (size_t)b * LMAXT * HD + g;

  // depth-4 named prefetch slots: pre-scaled W_ih contributions
  float p0r, p0z, p0n, p1r, p1z, p1n, p2r, p2z, p2n, p3r, p3z, p3n;
  {
    const float* r0 = W_ih + (size_t)seqL[0] * 192;
    p0r = fmaf(r0[g], -LOG2E, br2); p0z = fmaf(r0[64 + g], -LOG2E, bz2);
    p0n = fmaf(r0[128 + g], TWO_L2E, bn2);
    const float* r1 = W_ih + (size_t)seqL[1] * 192;
    p1r = fmaf(r1[g], -LOG2E, br2); p1z = fmaf(r1[64 + g], -LOG2E, bz2);
    p1n = fmaf(r1[128 + g], TWO_L2E, bn2);
    const float* r2 = W_ih + (size_t)seqL[2] * 192;
    p2r = fmaf(r2[g], -LOG2E, br2); p2z = fmaf(r2[64 + g], -LOG2E, bz2);
    p2n = fmaf(r2[128 + g], TWO_L2E, bn2);
    const float* r3 = W_ih + (size_t)seqL[3] * 192;
    p3r = fmaf(r3[g], -LOG2E, br2); p3z = fmaf(r3[64 + g], -LOG2E, bz2);
    p3n = fmaf(r3[128 + g], TWO_L2E, bn2);
  }

// GSTEP: loads issue at the TOP (before the ~400cyc DOT8 block), the
// pre-scale fmas consume them at the BOTTOM — within-step hoist only;
// prefetch-slot structure and cross-step state identical to R1/R9.
#define GSTEP(u) {                                                        \
    int nt_ = t + (u) + 4; nt_ = (nt_ <= LMAXT + 1) ? nt_ : (LMAXT + 1);  \
    const int sidx_ = seqL[nt_];                                          \
    const float* rw_ = W_ih + (size_t)sidx_ * 192;                        \
    const float lr_ = rw_[g];                                             \
    const float lz_ = rw_[64 + g];                                        \
    const float ln_ = rw_[128 + g];                                       \
    const h8* hp8 = (const h8*)hl;                                        \
    float sr0 = 0.f, sr1 = 0.f, sz0 = 0.f, sz1 = 0.f, sn0 = 0.f, sn1 = 0.f; \
    DOT8(0) DOT8(1) DOT8(2) DOT8(3) DOT8(4) DOT8(5) DOT8(6) DOT8(7)       \
    const float rr = frcp(1.f + ex2(fmaf(sr0 + sr1, -LOG2E, p##u##r)));   \
    const float zz = frcp(1.f + ex2(fmaf(sz0 + sz1, -LOG2E, p##u##z)));   \
    const float g2 = fmaf(sn0 + sn1, TWO_L2E, bhn2);                      \
    const float q  = frcp(1.f + ex2(fmaf(rr, g2, p##u##n)));              \
    const float th = fmaf(-2.f, q, 1.f);                                  \
    const float hn = fmaf(zz, hself - th, th);                            \
    hself = hn;                                                           \
    const _Float16 hh = (_Float16)hn;                                     \
    hl[g] = hh;                                                           \
    xptr[(size_t)(t + (u)) * HD] = __builtin_bit_cast(unsigned short, hh);\
    p##u##r = fmaf(lr_, -LOG2E, br2);                                     \
    p##u##z = fmaf(lz_, -LOG2E, bz2);                                     \
    p##u##n = fmaf(ln_, TWO_L2E, bn2); }

  const int ngroups = (nst + 3) >> 2;
  for (int tg = 0; tg < ngroups; ++tg) {
    const int t = tg * 4;
    GSTEP(0)
    GSTEP(1)
    GSTEP(2)
    GSTEP(3)
  }
#undef GSTEP

  // zero-fill padded rows (vectorized; overwrites the <=3 garbage tail rows)
  {
    uint4 z4; z4.x = 0u; z4.y = 0u; z4.z = 0u; z4.w = 0u;
    uint4* xz = (uint4*)(Xh + (size_t)b * (LMAXT * HD) + (size_t)nst * HD);
    const int n4 = (LMAXT - nst) * 8;      // 8 uint4 per 64-elem f16 row
    for (int i = g; i < n4; i += 64) xz[i] = z4;
  }
}

// ---------------------------------------------------------------------------
// Kernel C: MFMA f16 fused projection + logsumexp + NLL.
// Finalize folded in via device-scope atomic ticket (R2-verified).
// ---------------------------------------------------------------------------
__global__ __launch_bounds__(512)
__attribute__((amdgpu_waves_per_eu(4, 8)))
void k_proj(
    const unsigned short* __restrict__ Xh,
    const unsigned short* __restrict__ Wh,
    const float* __restrict__ bo2,
    const int* __restrict__ seq, const int* __restrict__ steps,
    const float* __restrict__ b_out,
    float* __restrict__ loss_accum, unsigned* __restrict__ ticket,
    float* __restrict__ out) {
  const int l  = threadIdx.x & 63;
  const int wv = threadIdx.x >> 6;         // 0..7 column-split wave id
  const int b  = blockIdx.x / 10;
  const int t0 = (blockIdx.x % 10) * 32;
  const int nst = steps[b];
  const bool active = (t0 < nst);          // block-uniform

  __shared__ float spart[CSPLIT][32];

  if (active) {
    const int lm = l & 15;
    const int q  = l >> 4;

    const unsigned short* xp0 = Xh + ((size_t)b * LMAXT + t0 + lm) * HD + q * 8;
    const h8 a00 = ldh8(xp0);
    const h8 a01 = ldh8(xp0 + 32);
    const h8 a10 = ldh8(xp0 + 16 * HD);
    const h8 a11 = ldh8(xp0 + 16 * HD + 32);

    float s[8];
#pragma unroll
    for (int i = 0; i < 8; ++i) s[i] = 0.f;

    const int ct0 = wv * 33;
    const int ct1 = (ct0 + 33 < NTILE) ? (ct0 + 33) : NTILE;   // wave 7: 26

    const unsigned short* wp = Wh + lm * 64 + q * 8;
    const float* bop = bo2 + lm;

    h8 b0 = ldh8(wp + (size_t)ct0 * 1024);
    h8 b1 = ldh8(wp + (size_t)ct0 * 1024 + 32);
    float bo = bop[ct0 * 16];
    for (int ct = ct0; ct < ct1; ++ct) {
      h8 nb0, nb1; float nbo;
      if (ct + 1 < ct1) {
        const unsigned short* wpn = wp + (size_t)(ct + 1) * 1024;
        nb0 = ldh8(wpn); nb1 = ldh8(wpn + 32); nbo = bop[(ct + 1) * 16];
      }
      f32x4 acc0 = {0.f, 0.f, 0.f, 0.f};
      f32x4 acc1 = {0.f, 0.f, 0.f, 0.f};
      acc0 = __builtin_amdgcn_mfma_f32_16x16x32_f16(a00, b0, acc0, 0, 0, 0);
      acc0 = __builtin_amdgcn_mfma_f32_16x16x32_f16(a01, b1, acc0, 0, 0, 0);
      acc1 = __builtin_amdgcn_mfma_f32_16x16x32_f16(a10, b0, acc1, 0, 0, 0);
      acc1 = __builtin_amdgcn_mfma_f32_16x16x32_f16(a11, b1, acc1, 0, 0, 0);
#pragma unroll
      for (int i = 0; i < 4; ++i) {
        s[i]     += ex2(fmaf(acc0[i], LOG2E, bo));
        s[4 + i] += ex2(fmaf(acc1[i], LOG2E, bo));
      }
      if (ct + 1 < ct1) { b0 = nb0; b1 = nb1; bo = nbo; }
    }

    // reduce across the 16 lanes (lm) sharing each row
#pragma unroll
    for (int m = 1; m < 16; m <<= 1) {
#pragma unroll
      for (int i = 0; i < 8; ++i) s[i] += __shfl_xor(s[i], m, 64);
    }
    // D-layout: lane holds rows q*4+i (tile0) / 16+q*4+i (tile1)
    if (lm == 0) {
#pragma unroll
      for (int i = 0; i < 4; ++i) {
        spart[wv][q * 4 + i]      = s[i];
        spart[wv][16 + q * 4 + i] = s[4 + i];
      }
    }
  }
  __syncthreads();

  float nll = 0.f;
  if (active && threadIdx.x < 32) {
    const int t = t0 + threadIdx.x;
    if (t < nst) {
      float ssum = 0.f;
#pragma unroll
      for (int c = 0; c < CSPLIT; ++c) ssum += spart[c][threadIdx.x];
      const int col = seq[b * SEQ_STRIDE + t + 1];
      // target logit from the SAME f16 operands (consistent cancellation)
      const unsigned short* xr = Xh + ((size_t)b * LMAXT + t) * HD;
      const unsigned short* wc = Wh + (size_t)(col >> 4) * 1024 + (col & 15) * 64;
      float tl = b_out[col];
#pragma unroll 16
      for (int k = 0; k < 64; ++k)
        tl = fmaf(h2f(xr[k]), h2f(wc[k]), tl);
      nll = (30.f + __logf(ssum)) - tl;
    }
  }
  if (threadIdx.x < 64) {
#pragma unroll
    for (int off = 32; off; off >>= 1) nll += __shfl_down(nll, off, 64);
    if (threadIdx.x == 0) {
      atomicAdd(loss_accum, nll);
      __threadfence();
      const unsigned old = atomicAdd(ticket, 1u);
      if (old == NBLK_PROJ - 1) {
        __threadfence();
        const float ls = atomicAdd(loss_accum, 0.f);   // coherent read
        int cnt = 0;
        for (int i = 0; i < NB; ++i) cnt += steps[i];
        out[0] = ls / (float)cnt;
      }
    }
  }
}

// ---------------------------------------------------------------------------
extern "C" void kernel_launch(void* const* d_in, const int* in_sizes, int n_in,
                              void* d_out, int out_size, void* d_ws,
                              size_t ws_size, hipStream_t stream) {
  const float* embeds  = (const float*)d_in[0];
  const float* true_fp = (const float*)d_in[1];
  const int*   perm    = (const int*)d_in[5];
  const float* W_ih    = (const float*)d_in[6];
  const float* b_ih    = (const float*)d_in[7];
  const float* W_hh    = (const float*)d_in[8];
  const float* b_hh    = (const float*)d_in[9];
  const float* W_out   = (const float*)d_in[10];
  const float* b_out   = (const float*)d_in[11];

  char*  ws     = (char*)d_ws;
  int*   seq    = (int*)(ws + SEQ_OFF);
  int*   steps  = (int*)(ws + STEPS_OFF);
  float* loss   = (float*)(ws + LOSS_OFF);
  unsigned* tick = (unsigned*)(ws + TICK_OFF);
  unsigned short* Xh = (unsigned short*)(ws + XB_OFF);
  unsigned short* Wh = (unsigned short*)(ws + WB_OFF);
  float* bo2    = (float*)(ws + BO_OFF);
  float* out    = (float*)d_out;

  k_front<<<NB + NTILE, 64, 0, stream>>>(
      embeds, true_fp, perm, W_ih, b_ih, W_hh, b_hh, W_out, b_out,
      seq, steps, Xh, Wh, bo2, loss, tick);
  k_proj<<<NBLK_PROJ, 512, 0, stream>>>(
      Xh, Wh, bo2, seq, steps, b_out, loss, tick, out);
}